// Round 5
// baseline (55.441 us; speedup 1.0000x reference)
//
#include <hip/hip_runtime.h>

#define CSC 2.88539008177792681f  // 2*log2(e)

typedef float v2f __attribute__((ext_vector_type(2)));

__device__ __forceinline__ float fast_exp2(float x) {
  return __builtin_amdgcn_exp2f(x);
}
__device__ __forceinline__ float fast_rcp(float x) {
  return __builtin_amdgcn_rcpf(x);
}
__device__ __forceinline__ v2f vfma(v2f a, v2f b, v2f c) {
  return __builtin_elementwise_fma(a, b, c);
}
__device__ __forceinline__ v2f vsplat(float s) {
  v2f r;
  r[0] = s;
  r[1] = s;
  return r;
}

// ---------------- projection (unchanged) ----------------
__global__ __launch_bounds__(256) void proj_kernel(
    const float* __restrict__ query, const float* __restrict__ key,
    const float* __restrict__ weight, float* __restrict__ Eq,
    float* __restrict__ EkT) {
  __shared__ __align__(16) float rows[16][128];
  __shared__ __align__(16) float tile[16][128];
  int blk = blockIdx.x;
  bool isK = blk >= 128;
  const float* src = isK ? key : query;
  int woff = isK ? 128 : 0;
  int row0 = (isK ? blk - 128 : blk) * 16;
  int tid = threadIdx.x;
#pragma unroll
  for (int i = 0; i < 8; ++i) {
    int f = i * 256 + tid;
    rows[f >> 7][f & 127] = src[(size_t)row0 * 128 + f];
  }
  __syncthreads();
  int e = tid & 127;
  int rh = (tid >> 7) * 8;  // wave-uniform
  float acc[8];
#pragma unroll
  for (int i = 0; i < 8; ++i) acc[i] = 0.f;
  const float4* wrow =
      reinterpret_cast<const float4*>(weight + (size_t)e * 256 + woff);
#pragma unroll 4
  for (int d4 = 0; d4 < 32; ++d4) {
    float4 wv = wrow[d4];
#pragma unroll
    for (int i = 0; i < 8; ++i) {
      float4 rv = *reinterpret_cast<const float4*>(&rows[rh + i][d4 * 4]);
      acc[i] = fmaf(rv.x, wv.x, acc[i]);
      acc[i] = fmaf(rv.y, wv.y, acc[i]);
      acc[i] = fmaf(rv.z, wv.z, acc[i]);
      acc[i] = fmaf(rv.w, wv.w, acc[i]);
    }
  }
  if (!isK) {
#pragma unroll
    for (int i = 0; i < 8; ++i)
      Eq[(size_t)(row0 + rh + i) * 128 + e] = fast_exp2(CSC * acc[i]);
  } else {
#pragma unroll
    for (int i = 0; i < 8; ++i) tile[rh + i][e] = fast_exp2(CSC * acc[i]);
    __syncthreads();
    int eo = tid >> 1;
    int rseg = (tid & 1) * 8;
    float4 v0 = make_float4(tile[rseg + 0][eo], tile[rseg + 1][eo],
                            tile[rseg + 2][eo], tile[rseg + 3][eo]);
    float4 v1 = make_float4(tile[rseg + 4][eo], tile[rseg + 5][eo],
                            tile[rseg + 6][eo], tile[rseg + 7][eo]);
    float* dst = EkT + (size_t)eo * 2048 + row0 + rseg;
    *reinterpret_cast<float4*>(dst) = v0;
    *reinterpret_cast<float4*>(dst + 4) = v1;
  }
}

// 4-way reciprocal combine over an e-quad, v2f-wide over 2 k.
// sum_e vT_e/(1+eq_e*ek_e) = num/den; all A>=1, den<=2^98, f32-safe.
__device__ __forceinline__ void quad4(const float4 eq, const float4 vt, v2f ek0,
                                      v2f ek1, v2f ek2, v2f ek3, v2f& acc) {
  v2f one = vsplat(1.f);
  v2f A0 = vfma(vsplat(eq.x), ek0, one);
  v2f A1 = vfma(vsplat(eq.y), ek1, one);
  v2f A2 = vfma(vsplat(eq.z), ek2, one);
  v2f A3 = vfma(vsplat(eq.w), ek3, one);
  v2f P01 = A0 * A1;
  v2f P23 = A2 * A3;
  v2f t01 = vfma(vsplat(vt.x), A1, vsplat(vt.y) * A0);
  v2f t23 = vfma(vsplat(vt.z), A3, vsplat(vt.w) * A2);
  v2f num = vfma(t23, P01, t01 * P23);
  v2f den = P01 * P23;
  v2f r;
  r[0] = fast_rcp(den[0]);
  r[1] = fast_rcp(den[1]);
  acc = vfma(num, r, acc);
}

// Attention: grid 256 (b = blk>>7, q0 = (blk&127)*8), 1024 threads (16 waves).
// Score: thread -> 2 consecutive k x 4 q (half-block per q-quad); exp2 + row
// partial sums fused in-register (no separate softmax pass). PV: wave w ->
// k-chunk [w*64,+64) x all 8 q; p broadcast via ds_read_b128.
__global__ __launch_bounds__(1024, 4) void attn_kernel(
    const float* __restrict__ Eq, const float* __restrict__ EkT,
    const float* __restrict__ vT, const float* __restrict__ value,
    float* __restrict__ out) {
  __shared__ __align__(16) float sc[8][1024];    // 32 KB: p values
  __shared__ __align__(16) v2f pout[16][8][64];  // 64 KB
  __shared__ float wsum[16][4];
  __shared__ float denom[8];

  int tid = threadIdx.x;
  int lane = tid & 63;
  int w = tid >> 6;
  int b = blockIdx.x >> 7;
  int q0 = (blockIdx.x & 127) * 8;
  int half = tid >> 9;  // 0: q rows 0..3, 1: q rows 4..7
  int kp = tid & 511;   // k-pair index; k = 2*kp, 2*kp+1
  int qh = half * 4;

  // ---- scores + exp + row partial sums ----
  {
    const float* ekp = EkT + (size_t)b * 1024 + 2 * kp;
    const float* eqb = Eq + (size_t)(b * 1024 + q0 + qh) * 128;
    v2f acc[4];
#pragma unroll
    for (int q = 0; q < 4; ++q) acc[q] = vsplat(0.f);
#pragma unroll 2
    for (int e = 0; e < 128; e += 4) {
      v2f ek0 = *reinterpret_cast<const v2f*>(ekp + (size_t)(e + 0) * 2048);
      v2f ek1 = *reinterpret_cast<const v2f*>(ekp + (size_t)(e + 1) * 2048);
      v2f ek2 = *reinterpret_cast<const v2f*>(ekp + (size_t)(e + 2) * 2048);
      v2f ek3 = *reinterpret_cast<const v2f*>(ekp + (size_t)(e + 3) * 2048);
      float4 vt4 = *reinterpret_cast<const float4*>(vT + e);  // uniform
#pragma unroll
      for (int q = 0; q < 4; ++q) {
        float4 eq4 =
            *reinterpret_cast<const float4*>(eqb + (size_t)q * 128 + e);
        quad4(eq4, vt4, ek0, ek1, ek2, ek3, acc[q]);
      }
    }
#pragma unroll
    for (int q = 0; q < 4; ++q) {
      v2f p;
      p[0] = fast_exp2(-CSC * acc[q][0]);
      p[1] = fast_exp2(-CSC * acc[q][1]);
      *reinterpret_cast<v2f*>(&sc[qh + q][2 * kp]) = p;
      float s = p[0] + p[1];
#pragma unroll
      for (int off = 32; off; off >>= 1) s += __shfl_xor(s, off);
      if (lane == 0) wsum[w][q] = s;
    }
  }
  __syncthreads();
  if (tid < 8) {
    int base = (tid >> 2) * 8;  // waves 0..7 hold q0..3, 8..15 hold q4..7
    float s = 0.f;
#pragma unroll
    for (int ww = 0; ww < 8; ++ww) s += wsum[base + ww][tid & 3];
    denom[tid] = s;
  }

  // ---- PV: wave w -> k in [w*64, w*64+64), all 8 q; lane -> v2f column ----
  {
    int kb = w * 64;
    v2f acc2[8];
#pragma unroll
    for (int q = 0; q < 8; ++q) acc2[q] = vsplat(0.f);
    const v2f* vp =
        reinterpret_cast<const v2f*>(value) + (size_t)b * 1024 * 64 + lane;
#pragma unroll 2
    for (int kk = 0; kk < 64; kk += 4) {
      v2f vv0 = vp[(size_t)(kb + kk + 0) * 64];
      v2f vv1 = vp[(size_t)(kb + kk + 1) * 64];
      v2f vv2 = vp[(size_t)(kb + kk + 2) * 64];
      v2f vv3 = vp[(size_t)(kb + kk + 3) * 64];
#pragma unroll
      for (int q = 0; q < 8; ++q) {
        float4 pp = *reinterpret_cast<const float4*>(&sc[q][kb + kk]);
        acc2[q] = vfma(vsplat(pp.x), vv0, acc2[q]);
        acc2[q] = vfma(vsplat(pp.y), vv1, acc2[q]);
        acc2[q] = vfma(vsplat(pp.z), vv2, acc2[q]);
        acc2[q] = vfma(vsplat(pp.w), vv3, acc2[q]);
      }
    }
#pragma unroll
    for (int q = 0; q < 8; ++q) pout[w][q][lane] = acc2[q];
  }
  __syncthreads();

  // ---- cross-wave reduce + normalize ----
  if (tid < 512) {
    int q = tid >> 6;
    v2f r = pout[0][q][lane];
#pragma unroll
    for (int ww = 1; ww < 16; ++ww) r = r + pout[ww][q][lane];
    float inv = fast_rcp(denom[q]);
    r[0] *= inv;
    r[1] *= inv;
    reinterpret_cast<v2f*>(out)[(size_t)(b * 1024 + q0 + q) * 64 + lane] = r;
  }
}

extern "C" void kernel_launch(void* const* d_in, const int* in_sizes, int n_in,
                              void* d_out, int out_size, void* d_ws,
                              size_t ws_size, hipStream_t stream) {
  const float* query = (const float*)d_in[0];
  const float* key = (const float*)d_in[1];
  const float* value = (const float*)d_in[2];
  const float* vT = (const float*)d_in[3];
  const float* weight = (const float*)d_in[4];
  float* out = (float*)d_out;
  float* Eq = (float*)d_ws;      // 2048*128 f32 = 1 MB (row-major [row][e])
  float* EkT = Eq + 2048 * 128;  // 128 x 2048 f32 = 1 MB (transposed [e][col])
  proj_kernel<<<256, 256, 0, stream>>>(query, key, weight, Eq, EkT);
  attn_kernel<<<256, 1024, 0, stream>>>(Eq, EkT, vT, value, out);
}